// Round 14
// baseline (61.165 us; speedup 1.0000x reference)
//
#include <hip/hip_runtime.h>

#define BTOT 4096
#define G 8               // batch items per block (one per wave)
#define NC 16
#define WIN 247
#define NBLK (BTOT / G)   // 512 blocks

typedef float v2f __attribute__((ext_vector_type(2)));

// W table in LDS, v2f {Wr,Wi} per (tap m, channel c); m = t+9.
#define F2IDX(m, c) ((m) * 16 + (c) + ((m) >> 6) * 8)
#define WTSZ 4272         // F2IDX(264,15)+1

// One conv step: n = (2*TT+SS)*4 + jj. x from this wave's LDS chunk ring.
#define CONV_STEP(TT, SS, GUARDED)                                                       \
    {                                                                                    \
        v2f xv = xlv[((TT) & 3) * 128 + ((SS) * 4 + jj) * 16 + c];                       \
        _Pragma("unroll")                                                                \
        for (int w = 0; w < 10; ++w)                                                     \
            acc[w] = __builtin_elementwise_fma(                                          \
                xv, win[((2 * (TT) + (SS)) * 4 + 9 - w) & 15], acc[w]);                  \
        _Pragma("unroll")                                                                \
        for (int d = 0; d < 4; ++d) {                                                    \
            const int mb = (2 * (TT) + (SS)) * 4 + 16 + d;                               \
            if (!(GUARDED) || mb <= 261)                                                 \
                win[((2 * (TT) + (SS)) * 4 + d) & 15] = WT[F2IDX(mb + jj, c)];           \
        }                                                                                \
    }

// ---------------- Kernel 1: conv (LDS chunk-ring, barrier-free) + nonlinearity + projections ----------------
__global__ __launch_bounds__(512, 4) void k_main(
    const float* __restrict__ x,
    const float* __restrict__ Wr, const float* __restrict__ Wi,
    const float* __restrict__ Wnl, const float* __restrict__ Wc,
    const float* __restrict__ Wor, const float* __restrict__ Woi,
    float* __restrict__ out, float2* __restrict__ p2)
{
    __shared__ v2f WT[WTSZ];            // 34176 B
    __shared__ float4 XL[G][4][64];     // 32768 B: per-wave 4-chunk ring (1 KB chunks)
    __shared__ float Mlds[4 * 16 * 17]; // 4352 B, stride 17
    __shared__ float WoS[2 * 160];      // 1280 B
    __shared__ float WcS[4];

    const int tid  = threadIdx.x;
    const int lane = tid & 63;
    const int wv   = tid >> 6;          // wave = one batch item (0..7)
    const int jj   = lane >> 4;         // n-residue 0..3
    const int c    = lane & 15;         // channel
    const int b0   = blockIdx.x * G;

    // ---- stage W table (zero-padded, fp32) ----
    for (int idx = tid; idx < 265 * 16; idx += 512) {
        int m = idx >> 4, cc = idx & 15;
        int t = m - 9;
        v2f v = (v2f)(0.f);
        if (t >= 0 && t < WIN) { v.x = Wr[cc * WIN + t]; v.y = Wi[cc * WIN + t]; }
        WT[F2IDX(m, cc)] = v;
    }
    // ---- zero-diagonal neighbor matrices, stride 17 ----
    for (int idx = tid; idx < 1024; idx += 512) {
        int m  = idx >> 8;
        int cc = (idx >> 4) & 15;
        int j  = idx & 15;
        float v = 0.f;
        if (j != cc) {
            int jp = j - (j > cc);
            v = Wnl[cc * 60 + (m >> 1) * 30 + (m & 1) * 15 + jp];
        }
        Mlds[m * 272 + cc * 17 + j] = v;
    }
    if (tid < 160) { WoS[tid] = Wor[tid]; WoS[160 + tid] = Woi[tid]; }
    if (tid < 4) WcS[tid] = Wc[tid];
    __syncthreads();

    // item x as float4: 512 per item; chunk t = float4 [t*64, t*64+64) (1 KB contiguous)
    const float4* gx = (const float4*)(x + (size_t)(b0 + wv) * 8192);
    v2f* xlv = (v2f*)&XL[wv][0][0];     // chunk slot k at v2f offset k*128

    v2f acc[10];
    v2f win[16];                        // W ring: slot s holds tap (slotbase≡s mod 16)+jj
    float4 chq[4];                      // in-flight chunk registers
    #pragma unroll
    for (int w = 0; w < 10; ++w) acc[w] = (v2f)(0.f);
    #pragma unroll
    for (int d = 0; d < 16; ++d) win[d] = WT[F2IDX(d + jj, c)];

    // prologue: issue chunks 0..3, stage chunk 0 (compiler emits counted vmcnt)
    chq[0] = gx[lane];
    chq[1] = gx[64 + lane];
    chq[2] = gx[128 + lane];
    chq[3] = gx[192 + lane];
    XL[wv][0][lane] = chq[0];

    // main loop: t = 0..27. Per phase: issue load(t+4); write chunk t+1 (arrived,
    // counted vmcnt by compiler); compute chunk t from LDS. No barriers.
    for (int tq = 0; tq < 7; ++tq) {
        #pragma unroll
        for (int k = 0; k < 4; ++k) {
            const int t = tq * 4 + k;
            chq[k] = gx[(t + 4) * 64 + lane];          // chunk t+4
            XL[wv][(k + 1) & 3][lane] = chq[(k + 1) & 3];  // chunk t+1
            CONV_STEP(t, 0, 0)
            CONV_STEP(t, 1, 0)
        }
    }
    // epilogue t = 28..31 (chunks 29..31 in chq[1..3])
    XL[wv][1][lane] = chq[1];
    CONV_STEP(28, 0, 1) CONV_STEP(28, 1, 1)
    XL[wv][2][lane] = chq[2];
    CONV_STEP(29, 0, 1) CONV_STEP(29, 1, 1)
    XL[wv][3][lane] = chq[3];
    CONV_STEP(30, 0, 1) CONV_STEP(30, 1, 1)
    CONV_STEP(31, 0, 1) CONV_STEP(31, 1, 1)

    // ---- reduce over jj (lane bits 4,5) ----
    #pragma unroll
    for (int w = 0; w < 10; ++w) {
        acc[w].x += __shfl_xor(acc[w].x, 16);  acc[w].x += __shfl_xor(acc[w].x, 32);
        acc[w].y += __shfl_xor(acc[w].y, 16);  acc[w].y += __shfl_xor(acc[w].y, 32);
    }

    __syncthreads();                    // all conv LDS traffic done -> safe to alias
    float* S    = (float*)WT;
    float* fbuf = S;                    // [b][c][{r,i}][w] : G*320 = 2560 f
    float* crS  = S + 2560;             // 1280 f
    float* ciS  = S + 3840;             // 1280 f

    // ---- amp nonlinearity (fully reduced in-register) ----
    if (lane < 16) {
        #pragma unroll
        for (int w = 0; w < 10; ++w) {
            float fr = acc[w].x, fi = acc[w].y;
            float a  = fr * fr + fi * fi;
            fbuf[wv * 320 + c * 20 + w]      = a * fr;
            fbuf[wv * 320 + c * 20 + 10 + w] = a * fi;
        }
    }
    __syncthreads();

    // ---- phase 3: neighbor einsum + coeff + output-window weights ----
    const float* M0r = Mlds;
    const float* M0i = Mlds + 272;
    const float* M1r = Mlds + 544;
    const float* M1i = Mlds + 816;
    for (int idx = tid; idx < G * 160; idx += 512) {
        int bb = idx / 160; int r = idx - bb * 160;
        int cc = r / 10;    int w = r - cc * 10;
        const float* f3 = fbuf + bb * 320;
        float s0 = 0.f, s1 = 0.f;
        #pragma unroll
        for (int j = 0; j < NC; ++j) {
            float f3r = f3[j * 20 + w];
            float f3i = f3[j * 20 + 10 + w];
            s0 = fmaf(f3r, M0r[cc * 17 + j], fmaf(f3i, M0i[cc * 17 + j], s0));
            s1 = fmaf(f3r, M1r[cc * 17 + j], fmaf(f3i, M1i[cc * 17 + j], s1));
        }
        float p0 = s0 * WcS[0] + s1 * WcS[1];
        float p1 = s0 * WcS[2] + s1 * WcS[3];
        crS[idx] = p0 * WoS[cc * 10 + w];
        ciS[idx] = p1 * WoS[160 + cc * 10 + w];
    }
    __syncthreads();

    // ---- phase 4: sum over w, raw out + per-half-block reduced BN partials ----
    if (tid < G * NC) {                 // tid = bb*16+cc, two waves
        int bb = tid >> 4; int cc = tid & 15;
        float orr = 0.f, oii = 0.f;
        #pragma unroll
        for (int w = 0; w < 10; ++w) {
            orr += crS[bb * 160 + cc * 10 + w];
            oii += ciS[bb * 160 + cc * 10 + w];
        }
        size_t o = ((size_t)(b0 + bb) * NC + cc) * 2;
        out[o]     = orr;
        out[o + 1] = oii;
        float s1 = orr + oii;
        float q1 = orr * orr + oii * oii;
        s1 += __shfl_xor(s1, 16);  s1 += __shfl_xor(s1, 32);   // reduce over 4 bb in wave
        q1 += __shfl_xor(q1, 16);  q1 += __shfl_xor(q1, 32);
        if ((tid & 63) < 16)
            p2[cc * (2 * NBLK) + blockIdx.x * 2 + (tid >> 6)] = make_float2(s1, q1);
    }
}

// ---------------- Kernel 2: BN stats (redundant per block, L2-hot) + apply ----------------
__global__ __launch_bounds__(256) void k_bn(
    const float2* __restrict__ p2,
    const float* __restrict__ gamma, const float* __restrict__ beta,
    float* __restrict__ out)
{
    __shared__ float A[16], Bb[16];
    const int tid = threadIdx.x;
    const int cch = tid >> 4;           // channel 0..15
    const int t   = tid & 15;

    float s = 0.f, q = 0.f;
    #pragma unroll 8
    for (int k = 0; k < (2 * NBLK) / 16; ++k) {   // 64 entries per thread
        float2 v = p2[cch * (2 * NBLK) + t + 16 * k];
        s += v.x; q += v.y;
    }
    #pragma unroll
    for (int off = 1; off < 16; off <<= 1) {
        s += __shfl_xor(s, off);
        q += __shfl_xor(q, off);
    }
    if (t == 0) {
        const float inv_n = 1.f / (BTOT * 2.f);
        float mu  = s * inv_n;
        float var = q * inv_n - mu * mu;
        float sc  = gamma[cch] * rsqrtf(var + 1e-5f);
        A[cch]  = sc;
        Bb[cch] = beta[cch] - mu * sc;
    }
    __syncthreads();

    // apply: out as float4 (channels cp, cp+1); 32768 float4 total, 512/block
    float4* o4 = (float4*)out;
    const int base = blockIdx.x * 512;
    #pragma unroll
    for (int i = 0; i < 2; ++i) {
        int f = base + i * 256 + tid;
        float4 v = o4[f];
        int cp = (f & 7) * 2;
        v.x = v.x * A[cp]     + Bb[cp];
        v.y = v.y * A[cp]     + Bb[cp];
        v.z = v.z * A[cp + 1] + Bb[cp + 1];
        v.w = v.w * A[cp + 1] + Bb[cp + 1];
        o4[f] = v;
    }
}

extern "C" void kernel_launch(void* const* d_in, const int* in_sizes, int n_in,
                              void* d_out, int out_size, void* d_ws, size_t ws_size,
                              hipStream_t stream)
{
    const float* x    = (const float*)d_in[0];
    const float* Wr   = (const float*)d_in[1];
    const float* Wi   = (const float*)d_in[2];
    const float* Wnl  = (const float*)d_in[3];
    const float* Wc   = (const float*)d_in[4];
    const float* Wor  = (const float*)d_in[5];
    const float* Woi  = (const float*)d_in[6];
    const float* gam  = (const float*)d_in[7];
    const float* bet  = (const float*)d_in[8];
    float* out = (float*)d_out;
    float2* p2 = (float2*)d_ws;         // 16 * 1024 float2 = 128 KB

    k_main<<<NBLK, 512, 0, stream>>>(x, Wr, Wi, Wnl, Wc, Wor, Woi, out, p2);
    k_bn<<<64, 256, 0, stream>>>(p2, gam, bet, out);
}

// Round 15
// 44.453 us; speedup vs baseline: 1.3759x; 1.3759x over previous
//
#include <hip/hip_runtime.h>

#define BTOT 4096
#define G 8               // batch items per block (one per wave)
#define NC 16
#define WIN 247
#define NBLK (BTOT / G)   // 512 blocks

typedef float v2f __attribute__((ext_vector_type(2)));

// W table in LDS, v2f {Wr,Wi} per (tap m, channel c); m = t+9.
#define F2IDX(m, c) ((m) * 16 + (c) + ((m) >> 6) * 8)
#define WTSZ 4272         // F2IDX(264,15)+1

// One conv step: n = (2*TT+SS)*4 + jj. x from this wave's LDS chunk ring.
#define CONV_STEP(TT, SS, GUARDED)                                                       \
    {                                                                                    \
        v2f xv = xlv[((TT) & 3) * 128 + ((SS) * 4 + jj) * 16 + c];                       \
        _Pragma("unroll")                                                                \
        for (int w = 0; w < 10; ++w)                                                     \
            acc[w] = __builtin_elementwise_fma(                                          \
                xv, win[((2 * (TT) + (SS)) * 4 + 9 - w) & 15], acc[w]);                  \
        _Pragma("unroll")                                                                \
        for (int d = 0; d < 4; ++d) {                                                    \
            const int mb = (2 * (TT) + (SS)) * 4 + 16 + d;                               \
            if (!(GUARDED) || mb <= 261)                                                 \
                win[((2 * (TT) + (SS)) * 4 + d) & 15] = WT[F2IDX(mb + jj, c)];           \
        }                                                                                \
    }

// ---------------- Kernel 1: conv (LDS chunk-ring, barrier-free) + nonlinearity + projections ----------------
__global__ __launch_bounds__(512, 2) void k_main(
    const float* __restrict__ x,
    const float* __restrict__ Wr, const float* __restrict__ Wi,
    const float* __restrict__ Wnl, const float* __restrict__ Wc,
    const float* __restrict__ Wor, const float* __restrict__ Woi,
    float* __restrict__ out, float2* __restrict__ p2)
{
    __shared__ v2f WT[WTSZ];            // 34176 B
    __shared__ float4 XL[G][4][64];     // 32768 B: per-wave 4-chunk ring (1 KB chunks)
    __shared__ float Mlds[4 * 16 * 17]; // 4352 B, stride 17
    __shared__ float WoS[2 * 160];      // 1280 B
    __shared__ float WcS[4];

    const int tid  = threadIdx.x;
    const int lane = tid & 63;
    const int wv   = tid >> 6;          // wave = one batch item (0..7)
    const int jj   = lane >> 4;         // n-residue 0..3
    const int c    = lane & 15;         // channel
    const int b0   = blockIdx.x * G;

    // ---- stage W table (zero-padded, fp32) ----
    for (int idx = tid; idx < 265 * 16; idx += 512) {
        int m = idx >> 4, cc = idx & 15;
        int t = m - 9;
        v2f v = (v2f)(0.f);
        if (t >= 0 && t < WIN) { v.x = Wr[cc * WIN + t]; v.y = Wi[cc * WIN + t]; }
        WT[F2IDX(m, cc)] = v;
    }
    // ---- zero-diagonal neighbor matrices, stride 17 ----
    for (int idx = tid; idx < 1024; idx += 512) {
        int m  = idx >> 8;
        int cc = (idx >> 4) & 15;
        int j  = idx & 15;
        float v = 0.f;
        if (j != cc) {
            int jp = j - (j > cc);
            v = Wnl[cc * 60 + (m >> 1) * 30 + (m & 1) * 15 + jp];
        }
        Mlds[m * 272 + cc * 17 + j] = v;
    }
    if (tid < 160) { WoS[tid] = Wor[tid]; WoS[160 + tid] = Woi[tid]; }
    if (tid < 4) WcS[tid] = Wc[tid];
    __syncthreads();

    // item x as float4: 512 per item; chunk t = float4 [t*64, t*64+64) (1 KB contiguous)
    const float4* gx = (const float4*)(x + (size_t)(b0 + wv) * 8192);
    v2f* xlv = (v2f*)&XL[wv][0][0];     // chunk slot k at v2f offset k*128

    v2f acc[10];
    v2f win[16];                        // W ring: slot s holds tap (slotbase≡s mod 16)+jj
    float4 chq[4];                      // in-flight chunk registers
    #pragma unroll
    for (int w = 0; w < 10; ++w) acc[w] = (v2f)(0.f);
    #pragma unroll
    for (int d = 0; d < 16; ++d) win[d] = WT[F2IDX(d + jj, c)];

    // prologue: issue chunks 0..3, stage chunk 0 (compiler emits counted vmcnt)
    chq[0] = gx[lane];
    chq[1] = gx[64 + lane];
    chq[2] = gx[128 + lane];
    chq[3] = gx[192 + lane];
    XL[wv][0][lane] = chq[0];

    // main loop: t = 0..27. Per phase: issue load(t+4); write chunk t+1 (arrived,
    // counted vmcnt by compiler); compute chunk t from LDS. No barriers.
    for (int tq = 0; tq < 7; ++tq) {
        #pragma unroll
        for (int k = 0; k < 4; ++k) {
            const int t = tq * 4 + k;
            chq[k] = gx[(t + 4) * 64 + lane];          // chunk t+4
            XL[wv][(k + 1) & 3][lane] = chq[(k + 1) & 3];  // chunk t+1
            CONV_STEP(t, 0, 0)
            CONV_STEP(t, 1, 0)
        }
    }
    // epilogue t = 28..31 (chunks 29..31 in chq[1..3])
    XL[wv][1][lane] = chq[1];
    CONV_STEP(28, 0, 1) CONV_STEP(28, 1, 1)
    XL[wv][2][lane] = chq[2];
    CONV_STEP(29, 0, 1) CONV_STEP(29, 1, 1)
    XL[wv][3][lane] = chq[3];
    CONV_STEP(30, 0, 1) CONV_STEP(30, 1, 1)
    CONV_STEP(31, 0, 1) CONV_STEP(31, 1, 1)

    // ---- reduce over jj (lane bits 4,5) ----
    #pragma unroll
    for (int w = 0; w < 10; ++w) {
        acc[w].x += __shfl_xor(acc[w].x, 16);  acc[w].x += __shfl_xor(acc[w].x, 32);
        acc[w].y += __shfl_xor(acc[w].y, 16);  acc[w].y += __shfl_xor(acc[w].y, 32);
    }

    __syncthreads();                    // all conv LDS traffic done -> safe to alias
    float* S    = (float*)WT;
    float* fbuf = S;                    // [b][c][{r,i}][w] : G*320 = 2560 f
    float* crS  = S + 2560;             // 1280 f
    float* ciS  = S + 3840;             // 1280 f

    // ---- amp nonlinearity (fully reduced in-register) ----
    if (lane < 16) {
        #pragma unroll
        for (int w = 0; w < 10; ++w) {
            float fr = acc[w].x, fi = acc[w].y;
            float a  = fr * fr + fi * fi;
            fbuf[wv * 320 + c * 20 + w]      = a * fr;
            fbuf[wv * 320 + c * 20 + 10 + w] = a * fi;
        }
    }
    __syncthreads();

    // ---- phase 3: neighbor einsum + coeff + output-window weights ----
    const float* M0r = Mlds;
    const float* M0i = Mlds + 272;
    const float* M1r = Mlds + 544;
    const float* M1i = Mlds + 816;
    for (int idx = tid; idx < G * 160; idx += 512) {
        int bb = idx / 160; int r = idx - bb * 160;
        int cc = r / 10;    int w = r - cc * 10;
        const float* f3 = fbuf + bb * 320;
        float s0 = 0.f, s1 = 0.f;
        #pragma unroll
        for (int j = 0; j < NC; ++j) {
            float f3r = f3[j * 20 + w];
            float f3i = f3[j * 20 + 10 + w];
            s0 = fmaf(f3r, M0r[cc * 17 + j], fmaf(f3i, M0i[cc * 17 + j], s0));
            s1 = fmaf(f3r, M1r[cc * 17 + j], fmaf(f3i, M1i[cc * 17 + j], s1));
        }
        float p0 = s0 * WcS[0] + s1 * WcS[1];
        float p1 = s0 * WcS[2] + s1 * WcS[3];
        crS[idx] = p0 * WoS[cc * 10 + w];
        ciS[idx] = p1 * WoS[160 + cc * 10 + w];
    }
    __syncthreads();

    // ---- phase 4: sum over w, raw out + per-half-block reduced BN partials ----
    if (tid < G * NC) {                 // tid = bb*16+cc, two waves
        int bb = tid >> 4; int cc = tid & 15;
        float orr = 0.f, oii = 0.f;
        #pragma unroll
        for (int w = 0; w < 10; ++w) {
            orr += crS[bb * 160 + cc * 10 + w];
            oii += ciS[bb * 160 + cc * 10 + w];
        }
        size_t o = ((size_t)(b0 + bb) * NC + cc) * 2;
        out[o]     = orr;
        out[o + 1] = oii;
        float s1 = orr + oii;
        float q1 = orr * orr + oii * oii;
        s1 += __shfl_xor(s1, 16);  s1 += __shfl_xor(s1, 32);   // reduce over 4 bb in wave
        q1 += __shfl_xor(q1, 16);  q1 += __shfl_xor(q1, 32);
        if ((tid & 63) < 16)
            p2[cc * (2 * NBLK) + blockIdx.x * 2 + (tid >> 6)] = make_float2(s1, q1);
    }
}

// ---------------- Kernel 2: BN stats (redundant per block, L2-hot) + apply ----------------
__global__ __launch_bounds__(256) void k_bn(
    const float2* __restrict__ p2,
    const float* __restrict__ gamma, const float* __restrict__ beta,
    float* __restrict__ out)
{
    __shared__ float A[16], Bb[16];
    const int tid = threadIdx.x;
    const int cch = tid >> 4;           // channel 0..15
    const int t   = tid & 15;

    float s = 0.f, q = 0.f;
    #pragma unroll 8
    for (int k = 0; k < (2 * NBLK) / 16; ++k) {   // 64 entries per thread
        float2 v = p2[cch * (2 * NBLK) + t + 16 * k];
        s += v.x; q += v.y;
    }
    #pragma unroll
    for (int off = 1; off < 16; off <<= 1) {
        s += __shfl_xor(s, off);
        q += __shfl_xor(q, off);
    }
    if (t == 0) {
        const float inv_n = 1.f / (BTOT * 2.f);
        float mu  = s * inv_n;
        float var = q * inv_n - mu * mu;
        float sc  = gamma[cch] * rsqrtf(var + 1e-5f);
        A[cch]  = sc;
        Bb[cch] = beta[cch] - mu * sc;
    }
    __syncthreads();

    // apply: out as float4 (channels cp, cp+1); 32768 float4 total, 512/block
    float4* o4 = (float4*)out;
    const int base = blockIdx.x * 512;
    #pragma unroll
    for (int i = 0; i < 2; ++i) {
        int f = base + i * 256 + tid;
        float4 v = o4[f];
        int cp = (f & 7) * 2;
        v.x = v.x * A[cp]     + Bb[cp];
        v.y = v.y * A[cp]     + Bb[cp];
        v.z = v.z * A[cp + 1] + Bb[cp + 1];
        v.w = v.w * A[cp + 1] + Bb[cp + 1];
        o4[f] = v;
    }
}

extern "C" void kernel_launch(void* const* d_in, const int* in_sizes, int n_in,
                              void* d_out, int out_size, void* d_ws, size_t ws_size,
                              hipStream_t stream)
{
    const float* x    = (const float*)d_in[0];
    const float* Wr   = (const float*)d_in[1];
    const float* Wi   = (const float*)d_in[2];
    const float* Wnl  = (const float*)d_in[3];
    const float* Wc   = (const float*)d_in[4];
    const float* Wor  = (const float*)d_in[5];
    const float* Woi  = (const float*)d_in[6];
    const float* gam  = (const float*)d_in[7];
    const float* bet  = (const float*)d_in[8];
    float* out = (float*)d_out;
    float2* p2 = (float2*)d_ws;         // 16 * 1024 float2 = 128 KB

    k_main<<<NBLK, 512, 0, stream>>>(x, Wr, Wi, Wnl, Wc, Wor, Woi, out, p2);
    k_bn<<<64, 256, 0, stream>>>(p2, gam, bet, out);
}